// Round 13
// baseline (186.213 us; speedup 1.0000x reference)
//
#include <hip/hip_runtime.h>
#include <hip/hip_bf16.h>

// Problem constants (B,S,D,H = 2,2048,2048,16 ; DPH = 128)
#define BB 2
#define HH 16
#define SS 2048
#define DD 2048
#define DPH_ 128
#define QBLK 256
#define KBLK 64
#define NT (SS / KBLK)   // 32

// LDS strides (bf16 elements)
#define KSTR 136   // K-LDS  [KBLK][KSTR]  (kv-major, dph contiguous)
#define VSTR 72    // Vt-LDS [DPH][VSTR]   (dph-major, kv contiguous)
#define PSTR 72    // P-LDS  per-wave [32][PSTR]

typedef __bf16 bf16x8 __attribute__((ext_vector_type(8)));
typedef unsigned short u16x8 __attribute__((ext_vector_type(8)));
typedef float f32x4 __attribute__((ext_vector_type(4)));

__device__ __forceinline__ unsigned f2bfbits32(float f) {
  unsigned u = __builtin_bit_cast(unsigned, f);
  u += 0x7FFFu + ((u >> 16) & 1u);   // RNE
  return u >> 16;
}
__device__ __forceinline__ unsigned short f2bfbits(float f) {
  return (unsigned short)f2bfbits32(f);
}
__device__ __forceinline__ __bf16 f2bf(float f) {
  unsigned short s = f2bfbits(f);
  return __builtin_bit_cast(__bf16, s);
}
__device__ __forceinline__ void nt_store4(const float4& v, float* p) {
  f32x4 t = {v.x, v.y, v.z, v.w};
  __builtin_nontemporal_store(t, (f32x4*)p);
}

// 16-lane all-reduce via DPP (VALU-only; round-12 proven).
template <int CTRL>
__device__ __forceinline__ float dpp_addf(float x) {
  int y = __builtin_amdgcn_mov_dpp(__builtin_bit_cast(int, x), CTRL, 0xF, 0xF, true);
  return x + __builtin_bit_cast(float, y);
}
template <int CTRL>
__device__ __forceinline__ float dpp_maxf(float x) {
  int y = __builtin_amdgcn_mov_dpp(__builtin_bit_cast(int, x), CTRL, 0xF, 0xF, true);
  return fmaxf(x, __builtin_bit_cast(float, y));
}
__device__ __forceinline__ float dpp_sum16(float x) {
  x = dpp_addf<0xB1>(x);    // quad_perm xor1
  x = dpp_addf<0x4E>(x);    // quad_perm xor2
  x = dpp_addf<0x124>(x);   // row_ror:4
  x = dpp_addf<0x128>(x);   // row_ror:8
  return x;
}
__device__ __forceinline__ float dpp_max16(float x) {
  x = dpp_maxf<0xB1>(x);
  x = dpp_maxf<0x4E>(x);
  x = dpp_maxf<0x124>(x);
  x = dpp_maxf<0x128>(x);
  return x;
}

// Slim preprocessor: q fp32 -> qb bf16 (scratch) + mask passthrough.
template <bool PRE>
__global__ __launch_bounds__(256)
void preproc(const float* __restrict__ q, const int* __restrict__ mask,
             __bf16* __restrict__ qb, float* __restrict__ omask) {
  const size_t i = (size_t)blockIdx.x * 256 + threadIdx.x;  // 1,048,576 total
  const size_t e = i * 8;
  if constexpr (PRE) {
    const float4 v0 = *(const float4*)(q + e);
    const float4 v1 = *(const float4*)(q + e + 4);
    u16x8 t;
    t[0] = f2bfbits(v0.x); t[1] = f2bfbits(v0.y);
    t[2] = f2bfbits(v0.z); t[3] = f2bfbits(v0.w);
    t[4] = f2bfbits(v1.x); t[5] = f2bfbits(v1.y);
    t[6] = f2bfbits(v1.z); t[7] = f2bfbits(v1.w);
    *(u16x8*)(qb + e) = t;
  }
  if (i < (size_t)BB * SS) omask[i] = (float)mask[i];
}

// Fused flash attention, 8 waves x 32 Q-rows = 256 Q-rows per block.
// Round-12 softmax/order, plus: K/V LDS DOUBLE-BUFFERED -> ONE barrier
// per K-tile (was 2). 1 block/CU (LDS 108.5 KB), 8 waves = same 8/CU
// occupancy as round-12's 2x4, but half the staging volume per q-row.
template <bool PRE>
__global__ __launch_bounds__(512, 2)
void attn_fused(const __bf16* __restrict__ qb, const float* __restrict__ qf,
                float* __restrict__ out, float* __restrict__ dot,
                float* __restrict__ pk, float* __restrict__ pv) {
  __shared__ __align__(16) __bf16 kls[2][KBLK * KSTR];   // 2 x 17408 B
  __shared__ __align__(16) __bf16 vls[2][DPH_ * VSTR];   // 2 x 18432 B
  __shared__ __align__(16) __bf16 pls[8 * 32 * PSTR];    // 36864 B  => 108544 B

  // XCD-bijective swizzle: all 8 qt-blocks of one (b,h) land on one XCD.
  const int bid = blockIdx.x;          // 256 blocks
  const int xcd = bid & 7;
  const int idx = bid >> 3;            // 0..31
  const int qt  = idx & 7;
  const int G   = (idx >> 3) * 8 + xcd;  // 0..31 = b*16+h
  const int h   = G & 15;
  const int b   = G >> 4;

  const int tid  = threadIdx.x;
  const int wid  = tid >> 6;    // 0..7
  const int lane = tid & 63;
  const int g    = lane >> 4;   // 0..3
  const int c    = lane & 15;   // 0..15

  const int qbase = qt * QBLK;
  const float scale = 0.08838834764831845f;  // 1/sqrt(128)

  const size_t headoff = (size_t)b * SS * DD + (size_t)h * DPH_;
  const __bf16* qbh = PRE ? qb + headoff : nullptr;
  const float*  qfh = qf + headoff;

  // Q fragments: wave's 32 rows = 2 subtiles u; A-layout row=c, k=st*32+8g+i.
  bf16x8 aq[2][4];
  #pragma unroll
  for (int u = 0; u < 2; ++u) {
    const int row = qbase + wid * 32 + u * 16 + c;
    if constexpr (PRE) {
      const __bf16* p = qbh + (size_t)row * DD + 8 * g;
      #pragma unroll
      for (int st = 0; st < 4; ++st) aq[u][st] = *(const bf16x8*)(p + st * 32);
    } else {
      const float* p = qfh + (size_t)row * DD + 8 * g;
      #pragma unroll
      for (int st = 0; st < 4; ++st) {
        u16x8 t;
        #pragma unroll
        for (int i2 = 0; i2 < 8; ++i2) t[i2] = f2bfbits(p[st * 32 + i2]);
        aq[u][st] = __builtin_bit_cast(bf16x8, t);
      }
    }
  }

  // ---- staging ownership: 512 threads cover the 64x128 tile; each thread
  //      owns ONE kv row (even rows: tid<256, odd: tid>=256) x 16-col chunk.
  const int r0 = (tid & 31) * 2 + (tid >> 8);
  const int oo = (tid >> 5) & 7;

  bf16x8 st0, st1;                   // staged row chunk (16 bf16)
  auto load_tile = [&](int kvb) {
    if constexpr (PRE) {
      const __bf16* pA = qbh + (size_t)(kvb + r0) * DD + 16 * oo;
      st0 = *(const bf16x8*)pA;
      st1 = *(const bf16x8*)(pA + 8);
    } else {
      const float* pA = qfh + (size_t)(kvb + r0) * DD + 16 * oo;
      u16x8 t0, t1;
      #pragma unroll
      for (int i2 = 0; i2 < 8; ++i2) {
        t0[i2] = f2bfbits(pA[i2]);
        t1[i2] = f2bfbits(pA[8 + i2]);
      }
      st0 = __builtin_bit_cast(bf16x8, t0);
      st1 = __builtin_bit_cast(bf16x8, t1);
    }
  };
  auto write_tile = [&](int bufi) {
    __bf16* kb = kls[bufi];
    __bf16* vb = vls[bufi];
    *(bf16x8*)(&kb[r0 * KSTR + 16 * oo])     = st0;
    *(bf16x8*)(&kb[r0 * KSTR + 16 * oo + 8]) = st1;
    // V^T: scalar b16 writes; lanes write 2B-contiguous -> 2-way = free
    #pragma unroll
    for (int j = 0; j < 8; ++j) {
      vb[(16 * oo + j) * VSTR + r0]     = st0[j];
      vb[(16 * oo + 8 + j) * VSTR + r0] = st1[j];
    }
  };

  const f32x4 zero4 = {0.f, 0.f, 0.f, 0.f};
  f32x4 o[2][8];
  #pragma unroll
  for (int u = 0; u < 2; ++u)
    #pragma unroll
    for (int t = 0; t < 8; ++t) o[u][t] = zero4;
  float m[2][4], l[2][4];
  #pragma unroll
  for (int u = 0; u < 2; ++u)
    #pragma unroll
    for (int r = 0; r < 4; ++r) { m[u][r] = -1e30f; l[u][r] = 0.0f; }

  float* __restrict__ dotb = dot + ((size_t)(b * HH + h) << 22);  // S*S = 2^22

  // Prologue: stage tile 0 into buffer 0
  load_tile(0);
  write_tile(0);
  __syncthreads();

  for (int kt = 0; kt < NT; ++kt) {
    const int kvbase = kt * KBLK;
    const int cur = kt & 1;

    // ---- QK^T: 16 B-frag reads, 32 MFMA (each bk feeds both u) ----
    f32x4 s[2][4];
    #pragma unroll
    for (int u = 0; u < 2; ++u)
      #pragma unroll
      for (int ct = 0; ct < 4; ++ct) s[u][ct] = zero4;
    __builtin_amdgcn_s_setprio(1);
    #pragma unroll
    for (int st = 0; st < 4; ++st) {
      #pragma unroll
      for (int ct = 0; ct < 4; ++ct) {
        bf16x8 bk = *(const bf16x8*)(&kls[cur][(ct * 16 + c) * KSTR + st * 32 + 8 * g]);
        #pragma unroll
        for (int u = 0; u < 2; ++u)
          s[u][ct] = __builtin_amdgcn_mfma_f32_16x16x32_bf16(aq[u][st], bk, s[u][ct], 0, 0, 0);
      }
    }
    __builtin_amdgcn_s_setprio(0);

    // ---- T14: issue next tile's global loads (complete under softmax+PV) --
    if (kt + 1 < NT) load_tile(kvbase + KBLK);

    // ---- scale + raw scores -> dot_prod (nontemporal) ----
    #pragma unroll
    for (int u = 0; u < 2; ++u) {
      #pragma unroll
      for (int ct = 0; ct < 4; ++ct) s[u][ct] *= scale;
      #pragma unroll
      for (int r = 0; r < 4; ++r) {
        float* dp = dotb + (size_t)(qbase + wid * 32 + u * 16 + 4 * g + r) * SS + kvbase + c;
        #pragma unroll
        for (int ct = 0; ct < 4; ++ct)
          __builtin_nontemporal_store(s[u][ct][r], dp + ct * 16);
      }
    }

    // ---- online softmax per u: DPP reduces + T13 defer-max (THR=8) ----
    #pragma unroll
    for (int u = 0; u < 2; ++u) {
      float mx[4];
      #pragma unroll
      for (int r = 0; r < 4; ++r) {
        float tm = fmaxf(fmaxf(s[u][0][r], s[u][1][r]), fmaxf(s[u][2][r], s[u][3][r]));
        mx[r] = dpp_max16(tm);
      }
      const bool need = (mx[0] > m[u][0] + 8.0f) | (mx[1] > m[u][1] + 8.0f) |
                        (mx[2] > m[u][2] + 8.0f) | (mx[3] > m[u][3] + 8.0f);
      if (__any(need)) {                       // wave-uniform, rare
        #pragma unroll
        for (int r = 0; r < 4; ++r) {
          const float mn = fmaxf(m[u][r], mx[r]);
          const float alpha = __expf(m[u][r] - mn);
          m[u][r] = mn;
          l[u][r] *= alpha;
          #pragma unroll
          for (int t = 0; t < 8; ++t) o[u][t][r] *= alpha;
        }
      }
      float rs[4] = {0.f, 0.f, 0.f, 0.f};
      #pragma unroll
      for (int ct = 0; ct < 4; ++ct) {
        #pragma unroll
        for (int r = 0; r < 4; ++r) {
          float p = __expf(s[u][ct][r] - m[u][r]);   // bounded by e^8
          s[u][ct][r] = p;
          rs[r] += p;
        }
      }
      #pragma unroll
      for (int r = 0; r < 4; ++r)
        l[u][r] += dpp_sum16(rs[r]);
      // P -> per-wave LDS region (same-wave read, no barrier needed)
      __bf16* pw = &pls[wid * 32 * PSTR];
      #pragma unroll
      for (int ct = 0; ct < 4; ++ct)
        #pragma unroll
        for (int r = 0; r < 4; ++r)
          pw[(u * 16 + 4 * g + r) * PSTR + ct * 16 + c] = f2bf(s[u][ct][r]);
    }

    // ---- PV: 16 B-frag reads + 4 A reads, 32 MFMA ----
    __builtin_amdgcn_s_setprio(1);
    #pragma unroll
    for (int kk = 0; kk < 2; ++kk) {
      bf16x8 ap[2];
      #pragma unroll
      for (int u = 0; u < 2; ++u)
        ap[u] = *(const bf16x8*)(&pls[wid * 32 * PSTR + (u * 16 + c) * PSTR + kk * 32 + 8 * g]);
      #pragma unroll
      for (int t = 0; t < 8; ++t) {
        bf16x8 bv = *(const bf16x8*)(&vls[cur][(t * 16 + c) * VSTR + kk * 32 + 8 * g]);
        #pragma unroll
        for (int u = 0; u < 2; ++u)
          o[u][t] = __builtin_amdgcn_mfma_f32_16x16x32_bf16(ap[u], bv, o[u][t], 0, 0, 0);
      }
    }
    __builtin_amdgcn_s_setprio(0);

    // ---- stage tile kt+1 into the other buffer; ONE barrier per kt ----
    if (kt + 1 < NT) write_tile(cur ^ 1);
    __syncthreads();
  }

  // ---- epilogue: normalize and store out[b][q][h*128+d] ----
  #pragma unroll
  for (int u = 0; u < 2; ++u)
    #pragma unroll
    for (int r = 0; r < 4; ++r) {
      float inv = 1.0f / l[u][r];
      float* op = out + (size_t)(b * SS + qbase + wid * 32 + u * 16 + 4 * g + r) * DD + h * DPH_ + c;
      #pragma unroll
      for (int t = 0; t < 8; ++t)
        __builtin_nontemporal_store(o[u][t][r] * inv, op + t * 16);
    }

  // ---- epilogue: exact-fp32 prev_key/prev_value for this block's rows ----
  {
    const size_t bh = (size_t)b * HH + h;
    const int col = (tid & 31) * 4;
    #pragma unroll
    for (int rr = 0; rr < 16; ++rr) {
      const int row = qbase + rr * 16 + (tid >> 5);
      const float4 v = *(const float4*)(qfh + (size_t)row * DD + col);
      nt_store4(v, pk + (bh * SS + row) * DPH_ + col);
      nt_store4(v, pv + (bh * SS + row) * DPH_ + col);
    }
  }
}

extern "C" void kernel_launch(void* const* d_in, const int* in_sizes, int n_in,
                              void* d_out, int out_size, void* d_ws, size_t ws_size,
                              hipStream_t stream) {
  const float* q    = (const float*)d_in[0];
  const int*   mask = (const int*)d_in[1];
  float* out = (float*)d_out;

  // Output layout (concatenated flat, fp32):
  float* o_out  = out;                 // [B,S,D]        8,388,608
  float* o_pk   = out + 8388608;       // [B,H,S,DPH]    8,388,608
  float* o_pv   = out + 16777216;      // [B,H,S,DPH]    8,388,608
  float* o_mask = out + 25165824;      // [B,S]              4,096
  float* o_dot  = out + 25169920;      // [B*H,S,S]    134,217,728

  const size_t need = (size_t)BB * SS * DD * sizeof(__bf16);  // 16.8 MB
  const dim3 agrid(256);  // 8 qt x 16 h x 2 b, XCD-swizzled in-kernel

  if (ws_size >= need) {
    __bf16* qbf = (__bf16*)d_ws;
    preproc<true><<<4096, 256, 0, stream>>>(q, mask, qbf, o_mask);
    attn_fused<true><<<agrid, 512, 0, stream>>>(qbf, q, o_out, o_dot, o_pk, o_pv);
  } else {
    preproc<false><<<4096, 256, 0, stream>>>(q, mask, nullptr, o_mask);
    attn_fused<false><<<agrid, 512, 0, stream>>>(nullptr, q, o_out, o_dot, o_pk, o_pv);
  }
}

// Round 14
// 174.913 us; speedup vs baseline: 1.0646x; 1.0646x over previous
//
#include <hip/hip_runtime.h>
#include <hip/hip_bf16.h>

// Problem constants (B,S,D,H = 2,2048,2048,16 ; DPH = 128)
#define BB 2
#define HH 16
#define SS 2048
#define DD 2048
#define DPH_ 128
#define QBLK 128
#define KBLK 64
#define NT (SS / KBLK)   // 32

// LDS strides (bf16 elements)
#define KSTR 136   // K-LDS  [KBLK][KSTR]  (kv-major, dph contiguous)
#define VSTR 72    // Vt-LDS [DPH][VSTR]   (dph-major, kv contiguous)
#define PSTR 72    // P-LDS  per-wave [32][PSTR]

typedef __bf16 bf16x8 __attribute__((ext_vector_type(8)));
typedef unsigned short u16x8 __attribute__((ext_vector_type(8)));
typedef float f32x4 __attribute__((ext_vector_type(4)));

__device__ __forceinline__ unsigned f2bfbits32(float f) {
  unsigned u = __builtin_bit_cast(unsigned, f);
  u += 0x7FFFu + ((u >> 16) & 1u);   // RNE
  return u >> 16;
}
__device__ __forceinline__ unsigned short f2bfbits(float f) {
  return (unsigned short)f2bfbits32(f);
}
__device__ __forceinline__ __bf16 f2bf(float f) {
  unsigned short s = f2bfbits(f);
  return __builtin_bit_cast(__bf16, s);
}
__device__ __forceinline__ void nt_store4(const float4& v, float* p) {
  f32x4 t = {v.x, v.y, v.z, v.w};
  __builtin_nontemporal_store(t, (f32x4*)p);
}

// 16-lane all-reduce via DPP (VALU-only; round-12 proven).
template <int CTRL>
__device__ __forceinline__ float dpp_addf(float x) {
  int y = __builtin_amdgcn_mov_dpp(__builtin_bit_cast(int, x), CTRL, 0xF, 0xF, true);
  return x + __builtin_bit_cast(float, y);
}
template <int CTRL>
__device__ __forceinline__ float dpp_maxf(float x) {
  int y = __builtin_amdgcn_mov_dpp(__builtin_bit_cast(int, x), CTRL, 0xF, 0xF, true);
  return fmaxf(x, __builtin_bit_cast(float, y));
}
__device__ __forceinline__ float dpp_sum16(float x) {
  x = dpp_addf<0xB1>(x);    // quad_perm xor1
  x = dpp_addf<0x4E>(x);    // quad_perm xor2
  x = dpp_addf<0x124>(x);   // row_ror:4
  x = dpp_addf<0x128>(x);   // row_ror:8
  return x;
}
__device__ __forceinline__ float dpp_max16(float x) {
  x = dpp_maxf<0xB1>(x);
  x = dpp_maxf<0x4E>(x);
  x = dpp_maxf<0x124>(x);
  x = dpp_maxf<0x128>(x);
  return x;
}

// Fused flash attention, 4 waves x 32 Q-rows = 128 Q-rows per block.
// EXACT round-12 structure (best, 179.8 us) with ONE change: no preproc
// kernel — Q-frags and K/V staging convert fp32->bf16 in-kernel (float4
// loads + packed RNE cvt; ~64 VALU-cy/wave/kt, hidden under the latency
// shadow), and the mask passthrough folds into block 0. Saves the serial
// ~10-12 us preproc dispatch and 34 MB of scratch traffic.
__global__ __launch_bounds__(256, 2)
void attn_fused(const float* __restrict__ qf, const int* __restrict__ maski,
                float* __restrict__ out, float* __restrict__ dot,
                float* __restrict__ pk, float* __restrict__ pv,
                float* __restrict__ omask) {
  __shared__ __bf16 kls[KBLK * KSTR];      // 17408 B
  __shared__ __bf16 vls[DPH_ * VSTR];      // 18432 B
  __shared__ __bf16 pls[4 * 32 * PSTR];    // 18432 B   total 54272 B

  // XCD-bijective swizzle: all 16 qt-blocks of one (b,h) land on one XCD.
  const int bid = blockIdx.x;
  const int xcd = bid & 7;
  const int t_  = bid >> 3;          // 0..63
  const int qt  = t_ & 15;
  const int G   = (t_ >> 4) * 8 + xcd;
  const int h   = G & 15;
  const int b   = G >> 4;

  const int tid  = threadIdx.x;
  const int wid  = tid >> 6;    // 0..3
  const int lane = tid & 63;
  const int g    = lane >> 4;   // 0..3
  const int c    = lane & 15;   // 0..15

  // mask passthrough (block 0 only; disjoint output range)
  if (bid == 0) {
    #pragma unroll
    for (int i = 0; i < 16; ++i)
      omask[tid + 256 * i] = (float)maski[tid + 256 * i];
  }

  const int qbase = qt * QBLK;
  const float scale = 0.08838834764831845f;  // 1/sqrt(128)

  const float* qfh = qf + (size_t)b * SS * DD + (size_t)h * DPH_;

  // Q fragments: wave's 32 rows = 2 subtiles u; A-layout row=c, k=st*32+8g+i.
  bf16x8 aq[2][4];
  #pragma unroll
  for (int u = 0; u < 2; ++u) {
    const int row = qbase + wid * 32 + u * 16 + c;
    const float* p = qfh + (size_t)row * DD + 8 * g;
    #pragma unroll
    for (int st = 0; st < 4; ++st) {
      const float4 f0 = *(const float4*)(p + st * 32);
      const float4 f1 = *(const float4*)(p + st * 32 + 4);
      u16x8 t;
      t[0] = f2bfbits(f0.x); t[1] = f2bfbits(f0.y);
      t[2] = f2bfbits(f0.z); t[3] = f2bfbits(f0.w);
      t[4] = f2bfbits(f1.x); t[5] = f2bfbits(f1.y);
      t[6] = f2bfbits(f1.z); t[7] = f2bfbits(f1.w);
      aq[u][st] = __builtin_bit_cast(bf16x8, t);
    }
  }

  // ---- staging ownership: thread owns kv rows r0,r0+1, dph [16oo,16oo+16) --
  const int p2 = tid & 31;
  const int oo = tid >> 5;           // 0..7
  const int r0 = 2 * p2;

  bf16x8 st0, st1, st2, st3;         // staged bf16: (r0: st0,st1) (r0+1: st2,st3)
  auto load_tile = [&](int kvb) {
    const float* pA = qfh + (size_t)(kvb + r0) * DD + 16 * oo;
    const float4 f0 = *(const float4*)pA;
    const float4 f1 = *(const float4*)(pA + 4);
    const float4 f2 = *(const float4*)(pA + 8);
    const float4 f3 = *(const float4*)(pA + 12);
    const float4 f4 = *(const float4*)(pA + DD);
    const float4 f5 = *(const float4*)(pA + DD + 4);
    const float4 f6 = *(const float4*)(pA + DD + 8);
    const float4 f7 = *(const float4*)(pA + DD + 12);
    u16x8 t0, t1, t2, t3;
    t0[0] = f2bfbits(f0.x); t0[1] = f2bfbits(f0.y);
    t0[2] = f2bfbits(f0.z); t0[3] = f2bfbits(f0.w);
    t0[4] = f2bfbits(f1.x); t0[5] = f2bfbits(f1.y);
    t0[6] = f2bfbits(f1.z); t0[7] = f2bfbits(f1.w);
    t1[0] = f2bfbits(f2.x); t1[1] = f2bfbits(f2.y);
    t1[2] = f2bfbits(f2.z); t1[3] = f2bfbits(f2.w);
    t1[4] = f2bfbits(f3.x); t1[5] = f2bfbits(f3.y);
    t1[6] = f2bfbits(f3.z); t1[7] = f2bfbits(f3.w);
    t2[0] = f2bfbits(f4.x); t2[1] = f2bfbits(f4.y);
    t2[2] = f2bfbits(f4.z); t2[3] = f2bfbits(f4.w);
    t2[4] = f2bfbits(f5.x); t2[5] = f2bfbits(f5.y);
    t2[6] = f2bfbits(f5.z); t2[7] = f2bfbits(f5.w);
    t3[0] = f2bfbits(f6.x); t3[1] = f2bfbits(f6.y);
    t3[2] = f2bfbits(f6.z); t3[3] = f2bfbits(f6.w);
    t3[4] = f2bfbits(f7.x); t3[5] = f2bfbits(f7.y);
    t3[6] = f2bfbits(f7.z); t3[7] = f2bfbits(f7.w);
    st0 = __builtin_bit_cast(bf16x8, t0);
    st1 = __builtin_bit_cast(bf16x8, t1);
    st2 = __builtin_bit_cast(bf16x8, t2);
    st3 = __builtin_bit_cast(bf16x8, t3);
  };
  auto write_tile = [&]() {
    *(bf16x8*)(&kls[r0 * KSTR + 16 * oo])       = st0;
    *(bf16x8*)(&kls[r0 * KSTR + 16 * oo + 8])   = st1;
    *(bf16x8*)(&kls[(r0+1) * KSTR + 16 * oo])     = st2;
    *(bf16x8*)(&kls[(r0+1) * KSTR + 16 * oo + 8]) = st3;
    // V^T: b32 writes packing the kv row-pair; conflict-free across lanes
    const unsigned* a0 = (const unsigned*)&st0;
    const unsigned* a1 = (const unsigned*)&st1;
    const unsigned* b0 = (const unsigned*)&st2;
    const unsigned* b1 = (const unsigned*)&st3;
    #pragma unroll
    for (int j = 0; j < 8; ++j) {
      unsigned loA = (j < 4 ? a0[j] : a1[j - 4]);
      unsigned loB = (j < 4 ? b0[j] : b1[j - 4]);
      unsigned w0 = (loA & 0xFFFFu) | (loB << 16);           // elem 2j
      unsigned w1 = (loA >> 16) | (loB & 0xFFFF0000u);       // elem 2j+1
      *(unsigned*)(&vls[(16 * oo + 2 * j) * VSTR + r0]) = w0;
      *(unsigned*)(&vls[(16 * oo + 2 * j + 1) * VSTR + r0]) = w1;
    }
  };

  const f32x4 zero4 = {0.f, 0.f, 0.f, 0.f};
  f32x4 o[2][8];
  #pragma unroll
  for (int u = 0; u < 2; ++u)
    #pragma unroll
    for (int t = 0; t < 8; ++t) o[u][t] = zero4;
  float m[2][4], l[2][4];
  #pragma unroll
  for (int u = 0; u < 2; ++u)
    #pragma unroll
    for (int r = 0; r < 4; ++r) { m[u][r] = -1e30f; l[u][r] = 0.0f; }

  float* __restrict__ dotb = dot + ((size_t)(b * HH + h) << 22);  // S*S = 2^22

  // Prologue: stage tile 0
  load_tile(0);
  write_tile();
  __syncthreads();

  for (int kt = 0; kt < NT; ++kt) {
    const int kvbase = kt * KBLK;

    // ---- QK^T: 16 B-frag reads, 32 MFMA (each bk feeds both u) ----
    f32x4 s[2][4];
    #pragma unroll
    for (int u = 0; u < 2; ++u)
      #pragma unroll
      for (int ct = 0; ct < 4; ++ct) s[u][ct] = zero4;
    __builtin_amdgcn_s_setprio(1);
    #pragma unroll
    for (int st = 0; st < 4; ++st) {
      #pragma unroll
      for (int ct = 0; ct < 4; ++ct) {
        bf16x8 bk = *(const bf16x8*)(&kls[(ct * 16 + c) * KSTR + st * 32 + 8 * g]);
        #pragma unroll
        for (int u = 0; u < 2; ++u)
          s[u][ct] = __builtin_amdgcn_mfma_f32_16x16x32_bf16(aq[u][st], bk, s[u][ct], 0, 0, 0);
      }
    }
    __builtin_amdgcn_s_setprio(0);

    // ---- T14: issue next tile's global loads (complete under softmax+PV) --
    if (kt + 1 < NT) load_tile(kvbase + KBLK);

    // ---- scale + raw scores -> dot_prod (nontemporal) ----
    #pragma unroll
    for (int u = 0; u < 2; ++u) {
      #pragma unroll
      for (int ct = 0; ct < 4; ++ct) s[u][ct] *= scale;
      #pragma unroll
      for (int r = 0; r < 4; ++r) {
        float* dp = dotb + (size_t)(qbase + wid * 32 + u * 16 + 4 * g + r) * SS + kvbase + c;
        #pragma unroll
        for (int ct = 0; ct < 4; ++ct)
          __builtin_nontemporal_store(s[u][ct][r], dp + ct * 16);
      }
    }

    // ---- online softmax per u: DPP reduces + T13 defer-max (THR=8) ----
    #pragma unroll
    for (int u = 0; u < 2; ++u) {
      float mx[4];
      #pragma unroll
      for (int r = 0; r < 4; ++r) {
        float tm = fmaxf(fmaxf(s[u][0][r], s[u][1][r]), fmaxf(s[u][2][r], s[u][3][r]));
        mx[r] = dpp_max16(tm);
      }
      const bool need = (mx[0] > m[u][0] + 8.0f) | (mx[1] > m[u][1] + 8.0f) |
                        (mx[2] > m[u][2] + 8.0f) | (mx[3] > m[u][3] + 8.0f);
      if (__any(need)) {                       // wave-uniform, rare
        #pragma unroll
        for (int r = 0; r < 4; ++r) {
          const float mn = fmaxf(m[u][r], mx[r]);
          const float alpha = __expf(m[u][r] - mn);
          m[u][r] = mn;
          l[u][r] *= alpha;
          #pragma unroll
          for (int t = 0; t < 8; ++t) o[u][t][r] *= alpha;
        }
      }
      float rs[4] = {0.f, 0.f, 0.f, 0.f};
      #pragma unroll
      for (int ct = 0; ct < 4; ++ct) {
        #pragma unroll
        for (int r = 0; r < 4; ++r) {
          float p = __expf(s[u][ct][r] - m[u][r]);   // bounded by e^8
          s[u][ct][r] = p;
          rs[r] += p;
        }
      }
      #pragma unroll
      for (int r = 0; r < 4; ++r)
        l[u][r] += dpp_sum16(rs[r]);
      // P -> per-wave LDS region (same-wave read, no barrier needed)
      __bf16* pw = &pls[wid * 32 * PSTR];
      #pragma unroll
      for (int ct = 0; ct < 4; ++ct)
        #pragma unroll
        for (int r = 0; r < 4; ++r)
          pw[(u * 16 + 4 * g + r) * PSTR + ct * 16 + c] = f2bf(s[u][ct][r]);
    }

    // ---- PV: 16 B-frag reads + 4 A reads, 32 MFMA ----
    __builtin_amdgcn_s_setprio(1);
    #pragma unroll
    for (int kk = 0; kk < 2; ++kk) {
      bf16x8 ap[2];
      #pragma unroll
      for (int u = 0; u < 2; ++u)
        ap[u] = *(const bf16x8*)(&pls[wid * 32 * PSTR + (u * 16 + c) * PSTR + kk * 32 + 8 * g]);
      #pragma unroll
      for (int t = 0; t < 8; ++t) {
        bf16x8 bv = *(const bf16x8*)(&vls[(t * 16 + c) * VSTR + kk * 32 + 8 * g]);
        #pragma unroll
        for (int u = 0; u < 2; ++u)
          o[u][t] = __builtin_amdgcn_mfma_f32_16x16x32_bf16(ap[u], bv, o[u][t], 0, 0, 0);
      }
    }
    __builtin_amdgcn_s_setprio(0);

    __syncthreads();                       // all waves done reading kls/vls
    if (kt + 1 < NT) write_tile();         // stage tile kt+1
    __syncthreads();
  }

  // ---- epilogue: normalize and store out[b][q][h*128+d] ----
  #pragma unroll
  for (int u = 0; u < 2; ++u)
    #pragma unroll
    for (int r = 0; r < 4; ++r) {
      float inv = 1.0f / l[u][r];
      float* op = out + (size_t)(b * SS + qbase + wid * 32 + u * 16 + 4 * g + r) * DD + h * DPH_ + c;
      #pragma unroll
      for (int t = 0; t < 8; ++t)
        __builtin_nontemporal_store(o[u][t][r] * inv, op + t * 16);
    }

  // ---- epilogue: exact-fp32 prev_key/prev_value for this block's rows ----
  {
    const size_t bh = (size_t)b * HH + h;
    const int col = (tid & 31) * 4;
    #pragma unroll
    for (int rr = 0; rr < 16; ++rr) {
      const int row = qbase + rr * 8 + (tid >> 5);
      const float4 v = *(const float4*)(qfh + (size_t)row * DD + col);
      nt_store4(v, pk + (bh * SS + row) * DPH_ + col);
      nt_store4(v, pv + (bh * SS + row) * DPH_ + col);
    }
  }
}

extern "C" void kernel_launch(void* const* d_in, const int* in_sizes, int n_in,
                              void* d_out, int out_size, void* d_ws, size_t ws_size,
                              hipStream_t stream) {
  const float* q    = (const float*)d_in[0];
  const int*   mask = (const int*)d_in[1];
  float* out = (float*)d_out;

  // Output layout (concatenated flat, fp32):
  float* o_out  = out;                 // [B,S,D]        8,388,608
  float* o_pk   = out + 8388608;       // [B,H,S,DPH]    8,388,608
  float* o_pv   = out + 16777216;      // [B,H,S,DPH]    8,388,608
  float* o_mask = out + 25165824;      // [B,S]              4,096
  float* o_dot  = out + 25169920;      // [B*H,S,S]    134,217,728

  // Single fused dispatch: 512 blocks = 16 qt x 16 h x 2 b, XCD-swizzled.
  attn_fused<<<dim3(512), dim3(256), 0, stream>>>(
      q, mask, o_out, o_dot, o_pk, o_pv, o_mask);
}

// Round 15
// 172.522 us; speedup vs baseline: 1.0794x; 1.0139x over previous
//
#include <hip/hip_runtime.h>
#include <hip/hip_bf16.h>

// Problem constants (B,S,D,H = 2,2048,2048,16 ; DPH = 128)
#define BB 2
#define HH 16
#define SS 2048
#define DD 2048
#define DPH_ 128
#define QBLK 128
#define KBLK 64
#define NT (SS / KBLK)   // 32

// LDS strides (bf16 elements)
#define KSTR 136   // K-LDS  [KBLK][KSTR]  (kv-major, dph contiguous)
#define VSTR 72    // Vt-LDS [DPH][VSTR]   (dph-major, kv contiguous)
#define PSTR 72    // P-LDS  per-wave [32][PSTR]

typedef __bf16 bf16x8 __attribute__((ext_vector_type(8)));
typedef unsigned short u16x8 __attribute__((ext_vector_type(8)));
typedef float f32x4 __attribute__((ext_vector_type(4)));

__device__ __forceinline__ unsigned f2bfbits32(float f) {
  unsigned u = __builtin_bit_cast(unsigned, f);
  u += 0x7FFFu + ((u >> 16) & 1u);   // RNE
  return u >> 16;
}
__device__ __forceinline__ unsigned short f2bfbits(float f) {
  return (unsigned short)f2bfbits32(f);
}
__device__ __forceinline__ __bf16 f2bf(float f) {
  unsigned short s = f2bfbits(f);
  return __builtin_bit_cast(__bf16, s);
}
__device__ __forceinline__ void nt_store4(const float4& v, float* p) {
  f32x4 t = {v.x, v.y, v.z, v.w};
  __builtin_nontemporal_store(t, (f32x4*)p);
}

// LDS-only barrier: orders ds ops across waves WITHOUT draining vmcnt.
// __syncthreads would emit s_waitcnt vmcnt(0) before s_barrier, forcing all
// waves to wait for the 32 in-flight nontemporal dot-stores + 4 staging
// loads at EVERY barrier (64/block). Those vmem ops need no cross-wave
// ordering (dot/pk/pv are never read; staging loads are consumed via
// register deps). sched_barrier(0) fences compiler motion (rule #18).
__device__ __forceinline__ void barrier_lds() {
  __builtin_amdgcn_sched_barrier(0);
  asm volatile("s_waitcnt lgkmcnt(0)" ::: "memory");
  __builtin_amdgcn_sched_barrier(0);
  __builtin_amdgcn_s_barrier();
  __builtin_amdgcn_sched_barrier(0);
}

// 16-lane all-reduce via DPP (VALU-only; round-12 proven).
template <int CTRL>
__device__ __forceinline__ float dpp_addf(float x) {
  int y = __builtin_amdgcn_mov_dpp(__builtin_bit_cast(int, x), CTRL, 0xF, 0xF, true);
  return x + __builtin_bit_cast(float, y);
}
template <int CTRL>
__device__ __forceinline__ float dpp_maxf(float x) {
  int y = __builtin_amdgcn_mov_dpp(__builtin_bit_cast(int, x), CTRL, 0xF, 0xF, true);
  return fmaxf(x, __builtin_bit_cast(float, y));
}
__device__ __forceinline__ float dpp_sum16(float x) {
  x = dpp_addf<0xB1>(x);    // quad_perm xor1
  x = dpp_addf<0x4E>(x);    // quad_perm xor2
  x = dpp_addf<0x124>(x);   // row_ror:4
  x = dpp_addf<0x128>(x);   // row_ror:8
  return x;
}
__device__ __forceinline__ float dpp_max16(float x) {
  x = dpp_maxf<0xB1>(x);
  x = dpp_maxf<0x4E>(x);
  x = dpp_maxf<0x124>(x);
  x = dpp_maxf<0x128>(x);
  return x;
}

// Fused flash attention, 4 waves x 32 Q-rows = 128 Q-rows per block.
// Round-14 structure (best, 174.9 us) with two changes:
//  (1) in-loop barriers are LDS-only (no vmcnt drain) -> NT stores and
//      prefetch loads stay in flight across all 64 barriers (T4 principle)
//  (2) scale folded into Q fragments once (removes 32 v_mul/thread/kt and
//      shortens the MFMA->dot-store chain); dot stores raw s directly.
__global__ __launch_bounds__(256, 2)
void attn_fused(const float* __restrict__ qf, const int* __restrict__ maski,
                float* __restrict__ out, float* __restrict__ dot,
                float* __restrict__ pk, float* __restrict__ pv,
                float* __restrict__ omask) {
  __shared__ __bf16 kls[KBLK * KSTR];      // 17408 B
  __shared__ __bf16 vls[DPH_ * VSTR];      // 18432 B
  __shared__ __bf16 pls[4 * 32 * PSTR];    // 18432 B   total 54272 B

  // XCD-bijective swizzle: all 16 qt-blocks of one (b,h) land on one XCD.
  const int bid = blockIdx.x;
  const int xcd = bid & 7;
  const int t_  = bid >> 3;          // 0..63
  const int qt  = t_ & 15;
  const int G   = (t_ >> 4) * 8 + xcd;
  const int h   = G & 15;
  const int b   = G >> 4;

  const int tid  = threadIdx.x;
  const int wid  = tid >> 6;    // 0..3
  const int lane = tid & 63;
  const int g    = lane >> 4;   // 0..3
  const int c    = lane & 15;   // 0..15

  // mask passthrough (block 0 only; disjoint output range)
  if (bid == 0) {
    #pragma unroll
    for (int i = 0; i < 16; ++i)
      omask[tid + 256 * i] = (float)maski[tid + 256 * i];
  }

  const int qbase = qt * QBLK;
  const float scale = 0.08838834764831845f;  // 1/sqrt(128)

  const float* qfh = qf + (size_t)b * SS * DD + (size_t)h * DPH_;

  // Q fragments (PRE-SCALED): wave's 32 rows = 2 subtiles u.
  bf16x8 aq[2][4];
  #pragma unroll
  for (int u = 0; u < 2; ++u) {
    const int row = qbase + wid * 32 + u * 16 + c;
    const float* p = qfh + (size_t)row * DD + 8 * g;
    #pragma unroll
    for (int st = 0; st < 4; ++st) {
      const float4 f0 = *(const float4*)(p + st * 32);
      const float4 f1 = *(const float4*)(p + st * 32 + 4);
      u16x8 t;
      t[0] = f2bfbits(f0.x * scale); t[1] = f2bfbits(f0.y * scale);
      t[2] = f2bfbits(f0.z * scale); t[3] = f2bfbits(f0.w * scale);
      t[4] = f2bfbits(f1.x * scale); t[5] = f2bfbits(f1.y * scale);
      t[6] = f2bfbits(f1.z * scale); t[7] = f2bfbits(f1.w * scale);
      aq[u][st] = __builtin_bit_cast(bf16x8, t);
    }
  }

  // ---- staging ownership: thread owns kv rows r0,r0+1, dph [16oo,16oo+16) --
  const int p2 = tid & 31;
  const int oo = tid >> 5;           // 0..7
  const int r0 = 2 * p2;

  bf16x8 st0, st1, st2, st3;         // staged bf16: (r0: st0,st1) (r0+1: st2,st3)
  auto load_tile = [&](int kvb) {
    const float* pA = qfh + (size_t)(kvb + r0) * DD + 16 * oo;
    const float4 f0 = *(const float4*)pA;
    const float4 f1 = *(const float4*)(pA + 4);
    const float4 f2 = *(const float4*)(pA + 8);
    const float4 f3 = *(const float4*)(pA + 12);
    const float4 f4 = *(const float4*)(pA + DD);
    const float4 f5 = *(const float4*)(pA + DD + 4);
    const float4 f6 = *(const float4*)(pA + DD + 8);
    const float4 f7 = *(const float4*)(pA + DD + 12);
    u16x8 t0, t1, t2, t3;
    t0[0] = f2bfbits(f0.x); t0[1] = f2bfbits(f0.y);
    t0[2] = f2bfbits(f0.z); t0[3] = f2bfbits(f0.w);
    t0[4] = f2bfbits(f1.x); t0[5] = f2bfbits(f1.y);
    t0[6] = f2bfbits(f1.z); t0[7] = f2bfbits(f1.w);
    t1[0] = f2bfbits(f2.x); t1[1] = f2bfbits(f2.y);
    t1[2] = f2bfbits(f2.z); t1[3] = f2bfbits(f2.w);
    t1[4] = f2bfbits(f3.x); t1[5] = f2bfbits(f3.y);
    t1[6] = f2bfbits(f3.z); t1[7] = f2bfbits(f3.w);
    t2[0] = f2bfbits(f4.x); t2[1] = f2bfbits(f4.y);
    t2[2] = f2bfbits(f4.z); t2[3] = f2bfbits(f4.w);
    t2[4] = f2bfbits(f5.x); t2[5] = f2bfbits(f5.y);
    t2[6] = f2bfbits(f5.z); t2[7] = f2bfbits(f5.w);
    t3[0] = f2bfbits(f6.x); t3[1] = f2bfbits(f6.y);
    t3[2] = f2bfbits(f6.z); t3[3] = f2bfbits(f6.w);
    t3[4] = f2bfbits(f7.x); t3[5] = f2bfbits(f7.y);
    t3[6] = f2bfbits(f7.z); t3[7] = f2bfbits(f7.w);
    st0 = __builtin_bit_cast(bf16x8, t0);
    st1 = __builtin_bit_cast(bf16x8, t1);
    st2 = __builtin_bit_cast(bf16x8, t2);
    st3 = __builtin_bit_cast(bf16x8, t3);
  };
  auto write_tile = [&]() {
    *(bf16x8*)(&kls[r0 * KSTR + 16 * oo])       = st0;
    *(bf16x8*)(&kls[r0 * KSTR + 16 * oo + 8])   = st1;
    *(bf16x8*)(&kls[(r0+1) * KSTR + 16 * oo])     = st2;
    *(bf16x8*)(&kls[(r0+1) * KSTR + 16 * oo + 8]) = st3;
    // V^T: b32 writes packing the kv row-pair; conflict-free across lanes
    const unsigned* a0 = (const unsigned*)&st0;
    const unsigned* a1 = (const unsigned*)&st1;
    const unsigned* b0 = (const unsigned*)&st2;
    const unsigned* b1 = (const unsigned*)&st3;
    #pragma unroll
    for (int j = 0; j < 8; ++j) {
      unsigned loA = (j < 4 ? a0[j] : a1[j - 4]);
      unsigned loB = (j < 4 ? b0[j] : b1[j - 4]);
      unsigned w0 = (loA & 0xFFFFu) | (loB << 16);           // elem 2j
      unsigned w1 = (loA >> 16) | (loB & 0xFFFF0000u);       // elem 2j+1
      *(unsigned*)(&vls[(16 * oo + 2 * j) * VSTR + r0]) = w0;
      *(unsigned*)(&vls[(16 * oo + 2 * j + 1) * VSTR + r0]) = w1;
    }
  };

  const f32x4 zero4 = {0.f, 0.f, 0.f, 0.f};
  f32x4 o[2][8];
  #pragma unroll
  for (int u = 0; u < 2; ++u)
    #pragma unroll
    for (int t = 0; t < 8; ++t) o[u][t] = zero4;
  float m[2][4], l[2][4];
  #pragma unroll
  for (int u = 0; u < 2; ++u)
    #pragma unroll
    for (int r = 0; r < 4; ++r) { m[u][r] = -1e30f; l[u][r] = 0.0f; }

  float* __restrict__ dotb = dot + ((size_t)(b * HH + h) << 22);  // S*S = 2^22

  // Prologue: stage tile 0
  load_tile(0);
  write_tile();
  __syncthreads();

  for (int kt = 0; kt < NT; ++kt) {
    const int kvbase = kt * KBLK;

    // ---- QK^T: 16 B-frag reads, 32 MFMA (each bk feeds both u) ----
    f32x4 s[2][4];
    #pragma unroll
    for (int u = 0; u < 2; ++u)
      #pragma unroll
      for (int ct = 0; ct < 4; ++ct) s[u][ct] = zero4;
    __builtin_amdgcn_s_setprio(1);
    #pragma unroll
    for (int st = 0; st < 4; ++st) {
      #pragma unroll
      for (int ct = 0; ct < 4; ++ct) {
        bf16x8 bk = *(const bf16x8*)(&kls[(ct * 16 + c) * KSTR + st * 32 + 8 * g]);
        #pragma unroll
        for (int u = 0; u < 2; ++u)
          s[u][ct] = __builtin_amdgcn_mfma_f32_16x16x32_bf16(aq[u][st], bk, s[u][ct], 0, 0, 0);
      }
    }
    __builtin_amdgcn_s_setprio(0);

    // ---- T14: issue next tile's global loads (complete under softmax+PV) --
    if (kt + 1 < NT) load_tile(kvbase + KBLK);

    // ---- raw (pre-scaled) scores -> dot_prod (nontemporal) ----
    #pragma unroll
    for (int u = 0; u < 2; ++u) {
      #pragma unroll
      for (int r = 0; r < 4; ++r) {
        float* dp = dotb + (size_t)(qbase + wid * 32 + u * 16 + 4 * g + r) * SS + kvbase + c;
        #pragma unroll
        for (int ct = 0; ct < 4; ++ct)
          __builtin_nontemporal_store(s[u][ct][r], dp + ct * 16);
      }
    }

    // ---- online softmax per u: DPP reduces + T13 defer-max (THR=8) ----
    #pragma unroll
    for (int u = 0; u < 2; ++u) {
      float mx[4];
      #pragma unroll
      for (int r = 0; r < 4; ++r) {
        float tm = fmaxf(fmaxf(s[u][0][r], s[u][1][r]), fmaxf(s[u][2][r], s[u][3][r]));
        mx[r] = dpp_max16(tm);
      }
      const bool need = (mx[0] > m[u][0] + 8.0f) | (mx[1] > m[u][1] + 8.0f) |
                        (mx[2] > m[u][2] + 8.0f) | (mx[3] > m[u][3] + 8.0f);
      if (__any(need)) {                       // wave-uniform, rare
        #pragma unroll
        for (int r = 0; r < 4; ++r) {
          const float mn = fmaxf(m[u][r], mx[r]);
          const float alpha = __expf(m[u][r] - mn);
          m[u][r] = mn;
          l[u][r] *= alpha;
          #pragma unroll
          for (int t = 0; t < 8; ++t) o[u][t][r] *= alpha;
        }
      }
      float rs[4] = {0.f, 0.f, 0.f, 0.f};
      #pragma unroll
      for (int ct = 0; ct < 4; ++ct) {
        #pragma unroll
        for (int r = 0; r < 4; ++r) {
          float p = __expf(s[u][ct][r] - m[u][r]);   // bounded by e^8
          s[u][ct][r] = p;
          rs[r] += p;
        }
      }
      #pragma unroll
      for (int r = 0; r < 4; ++r)
        l[u][r] += dpp_sum16(rs[r]);
      // P -> per-wave LDS region (same-wave read, no barrier needed)
      __bf16* pw = &pls[wid * 32 * PSTR];
      #pragma unroll
      for (int ct = 0; ct < 4; ++ct)
        #pragma unroll
        for (int r = 0; r < 4; ++r)
          pw[(u * 16 + 4 * g + r) * PSTR + ct * 16 + c] = f2bf(s[u][ct][r]);
    }

    // ---- PV: 16 B-frag reads + 4 A reads, 32 MFMA ----
    __builtin_amdgcn_s_setprio(1);
    #pragma unroll
    for (int kk = 0; kk < 2; ++kk) {
      bf16x8 ap[2];
      #pragma unroll
      for (int u = 0; u < 2; ++u)
        ap[u] = *(const bf16x8*)(&pls[wid * 32 * PSTR + (u * 16 + c) * PSTR + kk * 32 + 8 * g]);
      #pragma unroll
      for (int t = 0; t < 8; ++t) {
        bf16x8 bv = *(const bf16x8*)(&vls[(t * 16 + c) * VSTR + kk * 32 + 8 * g]);
        #pragma unroll
        for (int u = 0; u < 2; ++u)
          o[u][t] = __builtin_amdgcn_mfma_f32_16x16x32_bf16(ap[u], bv, o[u][t], 0, 0, 0);
      }
    }
    __builtin_amdgcn_s_setprio(0);

    barrier_lds();                         // all waves done reading kls/vls
    if (kt + 1 < NT) write_tile();         // stage tile kt+1
    barrier_lds();                         // writes visible to all waves
  }

  // ---- epilogue: normalize and store out[b][q][h*128+d] ----
  #pragma unroll
  for (int u = 0; u < 2; ++u)
    #pragma unroll
    for (int r = 0; r < 4; ++r) {
      float inv = 1.0f / l[u][r];
      float* op = out + (size_t)(b * SS + qbase + wid * 32 + u * 16 + 4 * g + r) * DD + h * DPH_ + c;
      #pragma unroll
      for (int t = 0; t < 8; ++t)
        __builtin_nontemporal_store(o[u][t][r] * inv, op + t * 16);
    }

  // ---- epilogue: exact-fp32 prev_key/prev_value for this block's rows ----
  {
    const size_t bh = (size_t)b * HH + h;
    const int col = (tid & 31) * 4;
    #pragma unroll
    for (int rr = 0; rr < 16; ++rr) {
      const int row = qbase + rr * 8 + (tid >> 5);
      const float4 v = *(const float4*)(qfh + (size_t)row * DD + col);
      nt_store4(v, pk + (bh * SS + row) * DPH_ + col);
      nt_store4(v, pv + (bh * SS + row) * DPH_ + col);
    }
  }
}

extern "C" void kernel_launch(void* const* d_in, const int* in_sizes, int n_in,
                              void* d_out, int out_size, void* d_ws, size_t ws_size,
                              hipStream_t stream) {
  const float* q    = (const float*)d_in[0];
  const int*   mask = (const int*)d_in[1];
  float* out = (float*)d_out;

  // Output layout (concatenated flat, fp32):
  float* o_out  = out;                 // [B,S,D]        8,388,608
  float* o_pk   = out + 8388608;       // [B,H,S,DPH]    8,388,608
  float* o_pv   = out + 16777216;      // [B,H,S,DPH]    8,388,608
  float* o_mask = out + 25165824;      // [B,S]              4,096
  float* o_dot  = out + 25169920;      // [B*H,S,S]    134,217,728

  // Single fused dispatch: 512 blocks = 16 qt x 16 h x 2 b, XCD-swizzled.
  attn_fused<<<dim3(512), dim3(256), 0, stream>>>(
      q, mask, o_out, o_dot, o_pk, o_pv, o_mask);
}